// Round 1
// baseline (5574.302 us; speedup 1.0000x reference)
//
#include <hip/hip_runtime.h>
#include <hip/hip_bf16.h>

#define BN      16000      // B*N nodes
#define NNODE   2000
#define NGRAPH  8
#define EPG     64000      // edges per graph
#define EB      (NGRAPH*EPG)   // 512000 batched edges
#define NNZ     (EB+BN)        // + self loops = 528000
#define TSTEPS  24
#define HOR     10
#define NSTEP   (HOR-1)

// ---- workspace layout (bytes) ----
#define OFF_EDGES   0            // uint2 * NNZ = 4,224,000
#define OFF_HA      4224000      // float * BN*64 = 4,096,000
#define OFF_HB      8320000
#define OFF_YIN     12416000     // float * BN
#define OFF_YB      12480000
#define OFF_KA      12544000
#define OFF_KB      12608000
#define OFF_KC      12672000
#define OFF_S4      12736000
#define OFF_DEG     12800000     // int * BN
#define OFF_CUR     12864000
#define OFF_ROWP    12928000     // int * (BN+1), padded
#define OFF_DINV    12992256     // float * BN
#define OFF_MODES   13056256     // int[2]: {fmode(1=bf16), imode(1=int64)}
#define OFF_WF      13056512     // fp32 weights, 12673 floats
// total ~13.11 MB

// fp32 weight pool offsets (elements)
#define W0OFF 0
#define B0OFF 64
#define W1OFF 128
#define B1OFF 4224
#define W2OFF 4288
#define B2OFF 8384
#define W3OFF 8448
#define B3OFF 12544
#define W4OFF 12608
#define B4OFF 12672
#define WFTOT 12673

struct WPtrs { const void* p[10]; };

__device__ inline float tanh_fast(float x) {
    float xc = fminf(fmaxf(x, -15.f), 15.f);
    float e  = __expf(2.f * xc);
    return 1.f - 2.f / (e + 1.f);
}

__device__ inline int ld_idx(const void* p, long i, int imode) {
    return imode ? (int)((const long long*)p)[i] : ((const int*)p)[i];
}

// ---- dtype detection: fmode from x exponent stats, imode from high words ----
__global__ void k_detect(const void* x, const void* eidx, int* modes) {
    int lane = threadIdx.x;  // 64 threads
    const unsigned* xw = (const unsigned*)x;
    unsigned w = xw[lane];
    int ex = (w >> 7) & 0xFF;                 // exponent of low-half-as-bf16
    unsigned long long m = __ballot(ex >= 100 && ex <= 145);
    const unsigned* ew = (const unsigned*)eidx;
    unsigned long long m2 = __ballot(ew[2*lane + 1] != 0);
    if (lane == 0) {
        modes[0] = (__popcll(m) >= 48) ? 1 : 0;   // bf16 floats?
        modes[1] = (__popcll(m2) == 0) ? 1 : 0;   // int64 indices?
    }
}

__global__ void k_init(int* deg) {
    int n = blockIdx.x * 256 + threadIdx.x;
    if (n < BN) deg[n] = 1;   // self-loop
}

__global__ void k_count(const void* eidx, const int* __restrict__ modes, int* deg) {
    int idx = blockIdx.x * 256 + threadIdx.x;   // exactly EB threads
    int imode = modes[1];
    int e = idx % EPG, g = idx / EPG;
    int dst = ld_idx(eidx, (long)EPG + e, imode);
    atomicAdd(&deg[g * NNODE + dst], 1);
}

__global__ __launch_bounds__(1024) void k_scan(const int* __restrict__ deg, int* rowp) {
    __shared__ int part[1024];
    int t = threadIdx.x, base = t * 16;
    int loc[16]; int s = 0;
    #pragma unroll
    for (int k = 0; k < 16; ++k) { int v = (base + k < BN) ? deg[base + k] : 0; loc[k] = v; s += v; }
    part[t] = s; __syncthreads();
    for (int off = 1; off < 1024; off <<= 1) {
        int v = (t >= off) ? part[t - off] : 0;
        __syncthreads();
        part[t] += v;
        __syncthreads();
    }
    int run = part[t] - s;
    #pragma unroll
    for (int k = 0; k < 16; ++k) { if (base + k < BN) rowp[base + k] = run; run += loc[k]; }
    if (t == 1023) rowp[BN] = part[1023];
}

__global__ void k_finalize(const int* __restrict__ deg, const int* __restrict__ rowp,
                           int* cursor, float* dinv, const void* x, const int* __restrict__ modes,
                           float* yin, float* yb, void* out) {
    int n = blockIdx.x * 256 + threadIdx.x;
    if (n >= BN) return;
    dinv[n] = rsqrtf((float)deg[n]);
    cursor[n] = rowp[n];
    float y0 = modes[0] ? __bfloat162float(((const __hip_bfloat16*)x)[n * TSTEPS + (TSTEPS - 1)])
                        : ((const float*)x)[n * TSTEPS + (TSTEPS - 1)];
    yin[n] = y0; yb[n] = y0;
    if (modes[0]) ((__hip_bfloat16*)out)[n * HOR] = __float2bfloat16(y0);
    else          ((float*)out)[n * HOR] = y0;
}

__global__ void k_convert(WPtrs wp, float* wf, const int* __restrict__ modes) {
    int idx = blockIdx.x * 256 + threadIdx.x;
    if (idx >= WFTOT) return;
    int fmode = modes[0];
    const int offs[10]  = {W0OFF,B0OFF,W1OFF,B1OFF,W2OFF,B2OFF,W3OFF,B3OFF,W4OFF,B4OFF};
    const int sizes[10] = {64,64,4096,64,4096,64,4096,64,64,1};
    #pragma unroll
    for (int s = 0; s < 10; ++s) {
        if (idx >= offs[s] && idx < offs[s] + sizes[s]) {
            int j = idx - offs[s];
            wf[idx] = fmode ? __bfloat162float(((const __hip_bfloat16*)wp.p[s])[j])
                            : ((const float*)wp.p[s])[j];
        }
    }
}

__global__ void k_scatter(const void* eidx, const int* __restrict__ modes,
                          const float* __restrict__ dinv, int* cursor, uint2* edges) {
    int idx = blockIdx.x * 256 + threadIdx.x;
    if (idx >= EB + BN) return;
    int imode = modes[1];
    if (idx < EB) {
        int e = idx % EPG, g = idx / EPG;
        int s = ld_idx(eidx, e, imode);
        int d = ld_idx(eidx, (long)EPG + e, imode);
        int sb = g * NNODE + s, db = g * NNODE + d;
        float v = dinv[sb] * dinv[db];
        int pos = atomicAdd(&cursor[db], 1);
        edges[pos] = make_uint2((unsigned)sb, __float_as_uint(v));
    } else {
        int n = idx - EB;
        float dv = dinv[n];
        int pos = atomicAdd(&cursor[n], 1);
        edges[pos] = make_uint2((unsigned)n, __float_as_uint(dv * dv));
    }
}

// ---- layer 0: h0[n][j] = tanh((Â y)[n] * W0[j] + b0[j]).  One wave per node. ----
__global__ __launch_bounds__(256) void k_layer0(
        const float* __restrict__ yin, float* __restrict__ hout,
        const uint2* __restrict__ edges, const int* __restrict__ rowp,
        const float* __restrict__ wf) {
    int lane = threadIdx.x & 63;
    int n = blockIdx.x * 4 + (threadIdx.x >> 6);   // 4000 blocks -> exactly BN waves
    float w0 = wf[W0OFF + lane], b0 = wf[B0OFF + lane];
    int s = rowp[n], e = rowp[n + 1];
    float acc = 0.f;
    for (int i = s + lane; i < e; i += 64) {
        uint2 ed = edges[i];
        acc += __uint_as_float(ed.y) * yin[ed.x];
    }
    #pragma unroll
    for (int off = 32; off; off >>= 1) acc += __shfl_xor(acc, off);
    hout[(n << 6) + lane] = tanh_fast(acc * w0 + b0);
}

// ---- middle layers: out[n][:] = tanh((Σ val*h[col])·W + b); FUSE adds W4 dot -> s4 ----
template<int FUSE>
__global__ __launch_bounds__(256, 4) void k_layer(
        const float* __restrict__ hin, float* __restrict__ hout, float* __restrict__ s4,
        const uint2* __restrict__ edges, const int* __restrict__ rowp,
        const float* __restrict__ wf, int woff, int boff) {
    __shared__ float aggbuf[4][64];
    int lane = threadIdx.x & 63, wv = threadIdx.x >> 6;
    int gw = blockIdx.x * 4 + wv;
    int nw = gridDim.x * 4;
    float Wreg[64];                       // column W[:, lane] in registers
    #pragma unroll
    for (int j = 0; j < 64; ++j) Wreg[j] = wf[woff + j * 64 + lane];
    float bias = wf[boff + lane];
    float w4 = FUSE ? wf[W4OFF + lane] : 0.f;

    for (int n = gw; n < BN; n += nw) {
        int s = rowp[n], e = rowp[n + 1];
        float acc = 0.f;
        int i = s;
        for (; i + 2 <= e; i += 2) {
            uint2 e0 = edges[i], e1 = edges[i + 1];
            float v0 = hin[(e0.x << 6) + lane];
            float v1 = hin[(e1.x << 6) + lane];
            acc += __uint_as_float(e0.y) * v0;
            acc += __uint_as_float(e1.y) * v1;
        }
        if (i < e) { uint2 e0 = edges[i]; acc += __uint_as_float(e0.y) * hin[(e0.x << 6) + lane]; }

        aggbuf[wv][lane] = acc;                    // wave-local LDS round-trip
        __builtin_amdgcn_wave_barrier();
        float o = bias;
        #pragma unroll
        for (int j = 0; j < 64; j += 4) {
            float4 a4 = *(const float4*)&aggbuf[wv][j];   // broadcast read
            o = fmaf(a4.x, Wreg[j + 0], o);
            o = fmaf(a4.y, Wreg[j + 1], o);
            o = fmaf(a4.z, Wreg[j + 2], o);
            o = fmaf(a4.w, Wreg[j + 3], o);
        }
        o = tanh_fast(o);
        if (FUSE) {
            float d = o * w4;                       // fused h3 @ W4 -> scalar
            #pragma unroll
            for (int off = 32; off; off >>= 1) d += __shfl_xor(d, off);
            if (lane == 0) s4[n] = d;
        } else {
            hout[(n << 6) + lane] = o;
        }
        __builtin_amdgcn_wave_barrier();
    }
}

// ---- final propagation (1 feat) + RK4 stage combination ----
__global__ __launch_bounds__(256) void k_prop(
        const float* __restrict__ s4, const uint2* __restrict__ edges, const int* __restrict__ rowp,
        const float* __restrict__ wf,
        float* yin, float* yb, float* kA, float* kB, float* kC,
        float c1, float c2, float c3, float c4, int stage,
        const int* __restrict__ modes, void* out, int hidx) {
    int lane = threadIdx.x & 63;
    int n = blockIdx.x * 4 + (threadIdx.x >> 6);
    int s = rowp[n], e = rowp[n + 1];
    float acc = 0.f;
    for (int i = s + lane; i < e; i += 64) {
        uint2 ed = edges[i];
        acc += __uint_as_float(ed.y) * s4[ed.x];
    }
    #pragma unroll
    for (int off = 32; off; off >>= 1) acc += __shfl_xor(acc, off);
    if (lane == 0) {
        float k = acc + wf[B4OFF];
        float ynew = yb[n] + c1 * kA[n] + c2 * kB[n] + c3 * kC[n] + c4 * k;
        if (stage == 0) kA[n] = k;
        else if (stage == 1) kB[n] = k;
        else if (stage == 2) kC[n] = k;
        yin[n] = ynew;
        if (stage == 3) {
            yb[n] = ynew;
            if (modes[0]) ((__hip_bfloat16*)out)[n * HOR + hidx] = __float2bfloat16(ynew);
            else          ((float*)out)[n * HOR + hidx] = ynew;
        }
    }
}

extern "C" void kernel_launch(void* const* d_in, const int* in_sizes, int n_in,
                              void* d_out, int out_size, void* d_ws, size_t ws_size,
                              hipStream_t stream) {
    char* ws = (char*)d_ws;
    uint2* edges = (uint2*)(ws + OFF_EDGES);
    float* hA   = (float*)(ws + OFF_HA);
    float* hB   = (float*)(ws + OFF_HB);
    float* yin  = (float*)(ws + OFF_YIN);
    float* yb   = (float*)(ws + OFF_YB);
    float* kA   = (float*)(ws + OFF_KA);
    float* kB   = (float*)(ws + OFF_KB);
    float* kC   = (float*)(ws + OFF_KC);
    float* s4   = (float*)(ws + OFF_S4);
    int*   deg  = (int*)(ws + OFF_DEG);
    int*   cur  = (int*)(ws + OFF_CUR);
    int*   rowp = (int*)(ws + OFF_ROWP);
    float* dinv = (float*)(ws + OFF_DINV);
    int*   modes= (int*)(ws + OFF_MODES);
    float* wf   = (float*)(ws + OFF_WF);

    const void* x    = d_in[0];
    const void* eidx = d_in[1];
    WPtrs wp;
    for (int i = 0; i < 10; ++i) wp.p[i] = d_in[2 + i];

    k_detect  <<<1, 64, 0, stream>>>(x, eidx, modes);
    k_init    <<<(BN + 255) / 256, 256, 0, stream>>>(deg);
    k_count   <<<EB / 256, 256, 0, stream>>>(eidx, modes, deg);
    k_scan    <<<1, 1024, 0, stream>>>(deg, rowp);
    k_finalize<<<(BN + 255) / 256, 256, 0, stream>>>(deg, rowp, cur, dinv, x, modes, yin, yb, d_out);
    k_convert <<<(WFTOT + 255) / 256, 256, 0, stream>>>(wp, wf, modes);
    k_scatter <<<(EB + BN + 255) / 256, 256, 0, stream>>>(eidx, modes, dinv, cur, edges);

    const float dt = 10.f / 9.f, dt3 = dt / 3.f;
    const float C[4][4] = {
        {0.f,        0.f,         0.f,         dt3},
        {-dt3,       0.f,         0.f,         dt},
        {dt,         -dt,         0.f,         dt},
        {dt * 0.125f, dt * 0.375f, dt * 0.375f, dt * 0.125f}
    };

    for (int step = 0; step < NSTEP; ++step) {
        for (int st = 0; st < 4; ++st) {
            k_layer0  <<<BN / 4, 256, 0, stream>>>(yin, hA, edges, rowp, wf);
            k_layer<0><<<1000, 256, 0, stream>>>(hA, hB, nullptr, edges, rowp, wf, W1OFF, B1OFF);
            k_layer<0><<<1000, 256, 0, stream>>>(hB, hA, nullptr, edges, rowp, wf, W2OFF, B2OFF);
            k_layer<1><<<1000, 256, 0, stream>>>(hA, nullptr, s4, edges, rowp, wf, W3OFF, B3OFF);
            k_prop    <<<BN / 4, 256, 0, stream>>>(s4, edges, rowp, wf, yin, yb, kA, kB, kC,
                                                   C[st][0], C[st][1], C[st][2], C[st][3], st,
                                                   modes, d_out, step + 1);
        }
    }
}

// Round 2
// 3958.026 us; speedup vs baseline: 1.4084x; 1.4084x over previous
//
#include <hip/hip_runtime.h>
#include <hip/hip_bf16.h>

#define BN      16000      // B*N nodes
#define NNODE   2000
#define NGRAPH  8
#define EPG     64000      // edges per graph
#define EB      (NGRAPH*EPG)   // 512000 batched edges
#define NNZ     (EB+BN)        // + self loops = 528000
#define TSTEPS  24
#define HOR     10
#define NSTEP   (HOR-1)

// ---- workspace layout (bytes) ----
#define OFF_EDGES   0            // uint2 * NNZ = 4,224,000
#define OFF_HA      4224000      // float * BN*64 = 4,096,000
#define OFF_HB      8320000
#define OFF_YIN     12416000     // float * BN
#define OFF_YB      12480000
#define OFF_KA      12544000
#define OFF_KB      12608000
#define OFF_KC      12672000
#define OFF_S4      12736000
#define OFF_DEG     12800000     // int * BN
#define OFF_CUR     12864000
#define OFF_ROWP    12928000     // int * (BN+1), padded
#define OFF_DINV    12992256     // float * BN
#define OFF_MODES   13056256     // int[2]: {fmode(1=bf16), imode(1=int64)}
#define OFF_WF      13056512     // fp32 weights, 12673 floats
// total ~13.11 MB

// fp32 weight pool offsets (elements)
#define W0OFF 0
#define B0OFF 64
#define W1OFF 128
#define B1OFF 4224
#define W2OFF 4288
#define B2OFF 8384
#define W3OFF 8448
#define B3OFF 12544
#define W4OFF 12608
#define B4OFF 12672
#define WFTOT 12673

struct WPtrs { const void* p[10]; };

__device__ inline float tanh_fast(float x) {
    float xc = fminf(fmaxf(x, -15.f), 15.f);
    float e  = __expf(2.f * xc);
    return 1.f - 2.f / (e + 1.f);
}

__device__ inline int ld_idx(const void* p, long i, int imode) {
    return imode ? (int)((const long long*)p)[i] : ((const int*)p)[i];
}

// ---- dtype detection: fmode from x exponent stats, imode from high words ----
__global__ void k_detect(const void* x, const void* eidx, int* modes) {
    int lane = threadIdx.x;  // 64 threads
    const unsigned* xw = (const unsigned*)x;
    unsigned w = xw[lane];
    int ex = (w >> 7) & 0xFF;                 // exponent of low-half-as-bf16
    unsigned long long m = __ballot(ex >= 100 && ex <= 145);
    const unsigned* ew = (const unsigned*)eidx;
    unsigned long long m2 = __ballot(ew[2*lane + 1] != 0);
    if (lane == 0) {
        modes[0] = (__popcll(m) >= 48) ? 1 : 0;   // bf16 floats?
        modes[1] = (__popcll(m2) == 0) ? 1 : 0;   // int64 indices?
    }
}

__global__ void k_init(int* deg) {
    int n = blockIdx.x * 256 + threadIdx.x;
    if (n < BN) deg[n] = 1;   // self-loop
}

__global__ void k_count(const void* eidx, const int* __restrict__ modes, int* deg) {
    int idx = blockIdx.x * 256 + threadIdx.x;   // exactly EB threads
    int imode = modes[1];
    int e = idx % EPG, g = idx / EPG;
    int dst = ld_idx(eidx, (long)EPG + e, imode);
    atomicAdd(&deg[g * NNODE + dst], 1);
}

__global__ __launch_bounds__(1024) void k_scan(const int* __restrict__ deg, int* rowp) {
    __shared__ int part[1024];
    int t = threadIdx.x, base = t * 16;
    int loc[16]; int s = 0;
    #pragma unroll
    for (int k = 0; k < 16; ++k) { int v = (base + k < BN) ? deg[base + k] : 0; loc[k] = v; s += v; }
    part[t] = s; __syncthreads();
    for (int off = 1; off < 1024; off <<= 1) {
        int v = (t >= off) ? part[t - off] : 0;
        __syncthreads();
        part[t] += v;
        __syncthreads();
    }
    int run = part[t] - s;
    #pragma unroll
    for (int k = 0; k < 16; ++k) { if (base + k < BN) rowp[base + k] = run; run += loc[k]; }
    if (t == 1023) rowp[BN] = part[1023];
}

__global__ void k_finalize(const int* __restrict__ deg, const int* __restrict__ rowp,
                           int* cursor, float* dinv, const void* x, const int* __restrict__ modes,
                           float* yin, float* yb, void* out) {
    int n = blockIdx.x * 256 + threadIdx.x;
    if (n >= BN) return;
    dinv[n] = rsqrtf((float)deg[n]);
    cursor[n] = rowp[n];
    float y0 = modes[0] ? __bfloat162float(((const __hip_bfloat16*)x)[n * TSTEPS + (TSTEPS - 1)])
                        : ((const float*)x)[n * TSTEPS + (TSTEPS - 1)];
    yin[n] = y0; yb[n] = y0;
    if (modes[0]) ((__hip_bfloat16*)out)[n * HOR] = __float2bfloat16(y0);
    else          ((float*)out)[n * HOR] = y0;
}

__global__ void k_convert(WPtrs wp, float* wf, const int* __restrict__ modes) {
    int idx = blockIdx.x * 256 + threadIdx.x;
    if (idx >= WFTOT) return;
    int fmode = modes[0];
    const int offs[10]  = {W0OFF,B0OFF,W1OFF,B1OFF,W2OFF,B2OFF,W3OFF,B3OFF,W4OFF,B4OFF};
    const int sizes[10] = {64,64,4096,64,4096,64,4096,64,64,1};
    #pragma unroll
    for (int s = 0; s < 10; ++s) {
        if (idx >= offs[s] && idx < offs[s] + sizes[s]) {
            int j = idx - offs[s];
            wf[idx] = fmode ? __bfloat162float(((const __hip_bfloat16*)wp.p[s])[j])
                            : ((const float*)wp.p[s])[j];
        }
    }
}

__global__ void k_scatter(const void* eidx, const int* __restrict__ modes,
                          const float* __restrict__ dinv, int* cursor, uint2* edges) {
    int idx = blockIdx.x * 256 + threadIdx.x;
    if (idx >= EB + BN) return;
    int imode = modes[1];
    if (idx < EB) {
        int e = idx % EPG, g = idx / EPG;
        int s = ld_idx(eidx, e, imode);
        int d = ld_idx(eidx, (long)EPG + e, imode);
        int sb = g * NNODE + s, db = g * NNODE + d;
        float v = dinv[sb] * dinv[db];
        int pos = atomicAdd(&cursor[db], 1);
        edges[pos] = make_uint2((unsigned)sb, __float_as_uint(v));
    } else {
        int n = idx - EB;
        float dv = dinv[n];
        int pos = atomicAdd(&cursor[n], 1);
        edges[pos] = make_uint2((unsigned)n, __float_as_uint(dv * dv));
    }
}

// ---- layer 0: h0[n][j] = tanh((Â y)[n] * W0[j] + b0[j]).  One wave per node. ----
__global__ __launch_bounds__(256) void k_layer0(
        const float* __restrict__ yin, float* __restrict__ hout,
        const uint2* __restrict__ edges, const int* __restrict__ rowp,
        const float* __restrict__ wf) {
    int lane = threadIdx.x & 63;
    int n = blockIdx.x * 4 + (threadIdx.x >> 6);   // 4000 blocks -> exactly BN waves
    float w0 = wf[W0OFF + lane], b0 = wf[B0OFF + lane];
    int s = rowp[n], e = rowp[n + 1];
    float acc = 0.f;
    for (int i = s + lane; i < e; i += 64) {
        uint2 ed = edges[i];
        acc += __uint_as_float(ed.y) * yin[ed.x];
    }
    #pragma unroll
    for (int off = 32; off; off >>= 1) acc += __shfl_xor(acc, off);
    hout[(n << 6) + lane] = tanh_fast(acc * w0 + b0);
}

// ---- middle layers: out[n][:] = tanh((Σ val*h[col])·W + b); FUSE adds W4 dot -> s4 ----
// Round 2: 8-wide predicated gather (8 outstanding 256B loads per wave) and
// W column held in float4 Wv[16] VGPRs; launch_bounds (256,3) so the 64-reg
// W column fits without rematerialization (R1: VGPR=48 => W was re-streamed).
template<int FUSE>
__global__ __launch_bounds__(256, 3) void k_layer(
        const float* __restrict__ hin, float* __restrict__ hout, float* __restrict__ s4,
        const uint2* __restrict__ edges, const int* __restrict__ rowp,
        const float* __restrict__ wf, int woff, int boff) {
    __shared__ float aggbuf[4][64];
    int lane = threadIdx.x & 63, wv = threadIdx.x >> 6;
    int gw = blockIdx.x * 4 + wv;
    int nw = gridDim.x * 4;
    float4 Wv[16];                       // column W[:, lane] in registers
    #pragma unroll
    for (int j = 0; j < 16; ++j) {
        Wv[j].x = wf[woff + (4 * j + 0) * 64 + lane];
        Wv[j].y = wf[woff + (4 * j + 1) * 64 + lane];
        Wv[j].z = wf[woff + (4 * j + 2) * 64 + lane];
        Wv[j].w = wf[woff + (4 * j + 3) * 64 + lane];
    }
    float bias = wf[boff + lane];
    float w4 = FUSE ? wf[W4OFF + lane] : 0.f;

    for (int n = gw; n < BN; n += nw) {
        int s = rowp[n], e = rowp[n + 1];
        float acc = 0.f;
        // predicated 8-wide gather: all 8 row loads independent & in flight
        for (int i = s; i < e; i += 8) {
            uint2 ed[8];
            #pragma unroll
            for (int k = 0; k < 8; ++k) {
                int idx = (i + k < e) ? (i + k) : (e - 1);
                ed[k] = edges[idx];
            }
            float v[8];
            #pragma unroll
            for (int k = 0; k < 8; ++k) v[k] = hin[(ed[k].x << 6) + lane];
            #pragma unroll
            for (int k = 0; k < 8; ++k) {
                float w = (i + k < e) ? __uint_as_float(ed[k].y) : 0.f;
                acc = fmaf(w, v[k], acc);
            }
        }

        aggbuf[wv][lane] = acc;                    // wave-local LDS round-trip
        __builtin_amdgcn_wave_barrier();
        float o = bias;
        #pragma unroll
        for (int j = 0; j < 16; ++j) {
            float4 a4 = *(const float4*)&aggbuf[wv][4 * j];   // broadcast read
            o = fmaf(a4.x, Wv[j].x, o);
            o = fmaf(a4.y, Wv[j].y, o);
            o = fmaf(a4.z, Wv[j].z, o);
            o = fmaf(a4.w, Wv[j].w, o);
        }
        o = tanh_fast(o);
        if (FUSE) {
            float d = o * w4;                       // fused h3 @ W4 -> scalar
            #pragma unroll
            for (int off = 32; off; off >>= 1) d += __shfl_xor(d, off);
            if (lane == 0) s4[n] = d;
        } else {
            hout[(n << 6) + lane] = o;
        }
        __builtin_amdgcn_wave_barrier();
    }
}

// ---- final propagation (1 feat) + RK4 stage combination ----
__global__ __launch_bounds__(256) void k_prop(
        const float* __restrict__ s4, const uint2* __restrict__ edges, const int* __restrict__ rowp,
        const float* __restrict__ wf,
        float* yin, float* yb, float* kA, float* kB, float* kC,
        float c1, float c2, float c3, float c4, int stage,
        const int* __restrict__ modes, void* out, int hidx) {
    int lane = threadIdx.x & 63;
    int n = blockIdx.x * 4 + (threadIdx.x >> 6);
    int s = rowp[n], e = rowp[n + 1];
    float acc = 0.f;
    for (int i = s + lane; i < e; i += 64) {
        uint2 ed = edges[i];
        acc += __uint_as_float(ed.y) * s4[ed.x];
    }
    #pragma unroll
    for (int off = 32; off; off >>= 1) acc += __shfl_xor(acc, off);
    if (lane == 0) {
        float k = acc + wf[B4OFF];
        float ynew = yb[n] + c1 * kA[n] + c2 * kB[n] + c3 * kC[n] + c4 * k;
        if (stage == 0) kA[n] = k;
        else if (stage == 1) kB[n] = k;
        else if (stage == 2) kC[n] = k;
        yin[n] = ynew;
        if (stage == 3) {
            yb[n] = ynew;
            if (modes[0]) ((__hip_bfloat16*)out)[n * HOR + hidx] = __float2bfloat16(ynew);
            else          ((float*)out)[n * HOR + hidx] = ynew;
        }
    }
}

extern "C" void kernel_launch(void* const* d_in, const int* in_sizes, int n_in,
                              void* d_out, int out_size, void* d_ws, size_t ws_size,
                              hipStream_t stream) {
    char* ws = (char*)d_ws;
    uint2* edges = (uint2*)(ws + OFF_EDGES);
    float* hA   = (float*)(ws + OFF_HA);
    float* hB   = (float*)(ws + OFF_HB);
    float* yin  = (float*)(ws + OFF_YIN);
    float* yb   = (float*)(ws + OFF_YB);
    float* kA   = (float*)(ws + OFF_KA);
    float* kB   = (float*)(ws + OFF_KB);
    float* kC   = (float*)(ws + OFF_KC);
    float* s4   = (float*)(ws + OFF_S4);
    int*   deg  = (int*)(ws + OFF_DEG);
    int*   cur  = (int*)(ws + OFF_CUR);
    int*   rowp = (int*)(ws + OFF_ROWP);
    float* dinv = (float*)(ws + OFF_DINV);
    int*   modes= (int*)(ws + OFF_MODES);
    float* wf   = (float*)(ws + OFF_WF);

    const void* x    = d_in[0];
    const void* eidx = d_in[1];
    WPtrs wp;
    for (int i = 0; i < 10; ++i) wp.p[i] = d_in[2 + i];

    k_detect  <<<1, 64, 0, stream>>>(x, eidx, modes);
    k_init    <<<(BN + 255) / 256, 256, 0, stream>>>(deg);
    k_count   <<<EB / 256, 256, 0, stream>>>(eidx, modes, deg);
    k_scan    <<<1, 1024, 0, stream>>>(deg, rowp);
    k_finalize<<<(BN + 255) / 256, 256, 0, stream>>>(deg, rowp, cur, dinv, x, modes, yin, yb, d_out);
    k_convert <<<(WFTOT + 255) / 256, 256, 0, stream>>>(wp, wf, modes);
    k_scatter <<<(EB + BN + 255) / 256, 256, 0, stream>>>(eidx, modes, dinv, cur, edges);

    const float dt = 10.f / 9.f, dt3 = dt / 3.f;
    const float C[4][4] = {
        {0.f,        0.f,         0.f,         dt3},
        {-dt3,       0.f,         0.f,         dt},
        {dt,         -dt,         0.f,         dt},
        {dt * 0.125f, dt * 0.375f, dt * 0.375f, dt * 0.125f}
    };

    for (int step = 0; step < NSTEP; ++step) {
        for (int st = 0; st < 4; ++st) {
            k_layer0  <<<BN / 4, 256, 0, stream>>>(yin, hA, edges, rowp, wf);
            k_layer<0><<<1000, 256, 0, stream>>>(hA, hB, nullptr, edges, rowp, wf, W1OFF, B1OFF);
            k_layer<0><<<1000, 256, 0, stream>>>(hB, hA, nullptr, edges, rowp, wf, W2OFF, B2OFF);
            k_layer<1><<<1000, 256, 0, stream>>>(hA, nullptr, s4, edges, rowp, wf, W3OFF, B3OFF);
            k_prop    <<<BN / 4, 256, 0, stream>>>(s4, edges, rowp, wf, yin, yb, kA, kB, kC,
                                                   C[st][0], C[st][1], C[st][2], C[st][3], st,
                                                   modes, d_out, step + 1);
        }
    }
}

// Round 3
// 3692.969 us; speedup vs baseline: 1.5094x; 1.0718x over previous
//
#include <hip/hip_runtime.h>
#include <hip/hip_bf16.h>

#define BN      16000      // B*N nodes
#define NNODE   2000
#define NGRAPH  8
#define EPG     64000      // edges per graph
#define EB      (NGRAPH*EPG)   // 512000 batched edges
#define NNZ     (EB+BN)        // + self loops = 528000
#define TSTEPS  24
#define HOR     10
#define NSTEP   (HOR-1)

// ---- workspace layout (bytes) ----
#define OFF_EDGES   0            // uint2 * NNZ = 4,224,000
#define OFF_HA      4224000      // float * BN*64 = 4,096,000
#define OFF_HB      8320000
#define OFF_YIN     12416000     // float * BN
#define OFF_YB      12480000
#define OFF_KA      12544000
#define OFF_KB      12608000
#define OFF_KC      12672000
#define OFF_S4      12736000
#define OFF_DEG     12800000     // int * BN
#define OFF_CUR     12864000
#define OFF_ROWP    12928000     // int * (BN+1), padded
#define OFF_DINV    12992256     // float * BN
#define OFF_MODES   13056256     // int[2]: {fmode(1=bf16), imode(1=int64)}
#define OFF_WF      13056512     // fp32 weights, 12673 floats -> ends 13107204
#define OFF_WFRAG   13107456    // bf16 hi/lo MFMA frags, 3 mats * 8192 shorts = 49152 B
// total ~13.16 MB

// fp32 weight pool offsets (elements)
#define W0OFF 0
#define B0OFF 64
#define W1OFF 128
#define B1OFF 4224
#define W2OFF 4288
#define B2OFF 8384
#define W3OFF 8448
#define B3OFF 12544
#define W4OFF 12608
#define B4OFF 12672
#define WFTOT 12673

typedef __attribute__((ext_vector_type(8))) short short8;
typedef __attribute__((ext_vector_type(4))) float f32x4;

struct WPtrs { const void* p[10]; };

__device__ inline float tanh_fast(float x) {
    float xc = fminf(fmaxf(x, -15.f), 15.f);
    float e  = __expf(2.f * xc);
    return 1.f - 2.f / (e + 1.f);
}

__device__ inline unsigned short f2bf(float f) {
    unsigned u = __float_as_uint(f);
    u += 0x7fff + ((u >> 16) & 1);        // RNE
    return (unsigned short)(u >> 16);
}
__device__ inline float bf2f(unsigned short h) {
    return __uint_as_float(((unsigned)h) << 16);
}

__device__ inline int ld_idx(const void* p, long i, int imode) {
    return imode ? (int)((const long long*)p)[i] : ((const int*)p)[i];
}

// ---- dtype detection: fmode from x exponent stats, imode from high words ----
__global__ void k_detect(const void* x, const void* eidx, int* modes) {
    int lane = threadIdx.x;  // 64 threads
    const unsigned* xw = (const unsigned*)x;
    unsigned w = xw[lane];
    int ex = (w >> 7) & 0xFF;                 // exponent of low-half-as-bf16
    unsigned long long m = __ballot(ex >= 100 && ex <= 145);
    const unsigned* ew = (const unsigned*)eidx;
    unsigned long long m2 = __ballot(ew[2*lane + 1] != 0);
    if (lane == 0) {
        modes[0] = (__popcll(m) >= 48) ? 1 : 0;   // bf16 floats?
        modes[1] = (__popcll(m2) == 0) ? 1 : 0;   // int64 indices?
    }
}

__global__ void k_init(int* deg) {
    int n = blockIdx.x * 256 + threadIdx.x;
    if (n < BN) deg[n] = 1;   // self-loop
}

__global__ void k_count(const void* eidx, const int* __restrict__ modes, int* deg) {
    int idx = blockIdx.x * 256 + threadIdx.x;   // exactly EB threads
    int imode = modes[1];
    int e = idx % EPG, g = idx / EPG;
    int dst = ld_idx(eidx, (long)EPG + e, imode);
    atomicAdd(&deg[g * NNODE + dst], 1);
}

__global__ __launch_bounds__(1024) void k_scan(const int* __restrict__ deg, int* rowp) {
    __shared__ int part[1024];
    int t = threadIdx.x, base = t * 16;
    int loc[16]; int s = 0;
    #pragma unroll
    for (int k = 0; k < 16; ++k) { int v = (base + k < BN) ? deg[base + k] : 0; loc[k] = v; s += v; }
    part[t] = s; __syncthreads();
    for (int off = 1; off < 1024; off <<= 1) {
        int v = (t >= off) ? part[t - off] : 0;
        __syncthreads();
        part[t] += v;
        __syncthreads();
    }
    int run = part[t] - s;
    #pragma unroll
    for (int k = 0; k < 16; ++k) { if (base + k < BN) rowp[base + k] = run; run += loc[k]; }
    if (t == 1023) rowp[BN] = part[1023];
}

__global__ void k_finalize(const int* __restrict__ deg, const int* __restrict__ rowp,
                           int* cursor, float* dinv, const void* x, const int* __restrict__ modes,
                           float* yin, float* yb, void* out) {
    int n = blockIdx.x * 256 + threadIdx.x;
    if (n >= BN) return;
    dinv[n] = rsqrtf((float)deg[n]);
    cursor[n] = rowp[n];
    float y0 = modes[0] ? __bfloat162float(((const __hip_bfloat16*)x)[n * TSTEPS + (TSTEPS - 1)])
                        : ((const float*)x)[n * TSTEPS + (TSTEPS - 1)];
    yin[n] = y0; yb[n] = y0;
    if (modes[0]) ((__hip_bfloat16*)out)[n * HOR] = __float2bfloat16(y0);
    else          ((float*)out)[n * HOR] = y0;
}

__global__ void k_convert(WPtrs wp, float* wf, const int* __restrict__ modes) {
    int idx = blockIdx.x * 256 + threadIdx.x;
    if (idx >= WFTOT) return;
    int fmode = modes[0];
    const int offs[10]  = {W0OFF,B0OFF,W1OFF,B1OFF,W2OFF,B2OFF,W3OFF,B3OFF,W4OFF,B4OFF};
    const int sizes[10] = {64,64,4096,64,4096,64,4096,64,64,1};
    #pragma unroll
    for (int s = 0; s < 10; ++s) {
        if (idx >= offs[s] && idx < offs[s] + sizes[s]) {
            int j = idx - offs[s];
            wf[idx] = fmode ? __bfloat162float(((const __hip_bfloat16*)wp.p[s])[j])
                            : ((const float*)wp.p[s])[j];
        }
    }
}

// ---- precompute MFMA B-fragments for W1,W2,W3: bf16 hi/lo split, frag-ordered ----
// frag[t] layout: t = mat*1024 + nb*256 + kh*128 + half*64 + lane, each a short8.
// value j: k = kh*32 + (lane>>4)*8 + j, n = nb*16 + (lane&15); B-frag: lane holds B[k][n].
__global__ void k_mkfrag(const float* __restrict__ wf, short8* frag) {
    int t = blockIdx.x * 256 + threadIdx.x;
    if (t >= 3072) return;
    int lane = t & 63, half = (t >> 6) & 1, kh = (t >> 7) & 1, nb = (t >> 8) & 3, mat = t >> 10;
    const int woffs[3] = {W1OFF, W2OFF, W3OFF};
    const float* W = wf + woffs[mat];
    int n  = nb * 16 + (lane & 15);
    int k0 = kh * 32 + (lane >> 4) * 8;
    short8 v;
    #pragma unroll
    for (int j = 0; j < 8; ++j) {
        float w = W[(k0 + j) * 64 + n];
        unsigned short h = f2bf(w);
        v[j] = half ? (short)f2bf(w - bf2f(h)) : (short)h;
    }
    frag[t] = v;
}

__global__ void k_scatter(const void* eidx, const int* __restrict__ modes,
                          const float* __restrict__ dinv, int* cursor, uint2* edges) {
    int idx = blockIdx.x * 256 + threadIdx.x;
    if (idx >= EB + BN) return;
    int imode = modes[1];
    if (idx < EB) {
        int e = idx % EPG, g = idx / EPG;
        int s = ld_idx(eidx, e, imode);
        int d = ld_idx(eidx, (long)EPG + e, imode);
        int sb = g * NNODE + s, db = g * NNODE + d;
        float v = dinv[sb] * dinv[db];
        int pos = atomicAdd(&cursor[db], 1);
        edges[pos] = make_uint2((unsigned)sb, __float_as_uint(v));
    } else {
        int n = idx - EB;
        float dv = dinv[n];
        int pos = atomicAdd(&cursor[n], 1);
        edges[pos] = make_uint2((unsigned)n, __float_as_uint(dv * dv));
    }
}

// ---- layer 0: h0[n][j] = tanh((Â y)[n] * W0[j] + b0[j]).  One wave per node. ----
__global__ __launch_bounds__(256) void k_layer0(
        const float* __restrict__ yin, float* __restrict__ hout,
        const uint2* __restrict__ edges, const int* __restrict__ rowp,
        const float* __restrict__ wf) {
    int lane = threadIdx.x & 63;
    int n = blockIdx.x * 4 + (threadIdx.x >> 6);   // 4000 blocks -> exactly BN waves
    float w0 = wf[W0OFF + lane], b0 = wf[B0OFF + lane];
    int s = rowp[n], e = rowp[n + 1];
    float acc = 0.f;
    for (int i = s + lane; i < e; i += 64) {
        uint2 ed = edges[i];
        acc += __uint_as_float(ed.y) * yin[ed.x];
    }
    #pragma unroll
    for (int off = 32; off; off >>= 1) acc += __shfl_xor(acc, off);
    hout[(n << 6) + lane] = tanh_fast(acc * w0 + b0);
}

// ---- middle layers (R3): block = one 16-node tile; gather -> LDS tile -> MFMA.
// Wave wv gathers nodes tbase+wv*4..+3 (lane=feature, fp32, 8-wide MLP),
// then computes output-feature block nb=wv via bf16x3-split MFMA with W frags
// streamed from precomputed global buffer (16 KB/block, was 16 KB/node in R2).
template<int FUSE>
__global__ __launch_bounds__(256, 4) void k_layer(
        const float* __restrict__ hin, float* __restrict__ hout, float* __restrict__ s4,
        const uint2* __restrict__ edges, const int* __restrict__ rowp,
        const float* __restrict__ wf, const short8* __restrict__ frag,
        int mat, int boff) {
    __shared__ float tile[16 * 68];     // agg rows, 68-float pitch (bank-friendly)
    __shared__ float pd[4][16];         // FUSE partials
    int lane = threadIdx.x & 63, wv = threadIdx.x >> 6;
    int tbase = blockIdx.x << 4;

    // B fragments for this wave's output block (nb = wv): 4 coalesced 16B/lane loads
    const short8* fb = frag + (mat << 10);
    short8 Bh0 = fb[(wv << 8) + 0 * 128 + 0 * 64 + lane];
    short8 Bl0 = fb[(wv << 8) + 0 * 128 + 1 * 64 + lane];
    short8 Bh1 = fb[(wv << 8) + 1 * 128 + 0 * 64 + lane];
    short8 Bl1 = fb[(wv << 8) + 1 * 128 + 1 * 64 + lane];

    // ---- gather phase: 4 nodes per wave ----
    #pragma unroll
    for (int r = 0; r < 4; ++r) {
        int m = (wv << 2) + r;          // tile row
        int n = tbase + m;
        int s = rowp[n], e = rowp[n + 1];
        float acc = 0.f;
        for (int i = s; i < e; i += 8) {
            uint2 ed[8];
            #pragma unroll
            for (int k = 0; k < 8; ++k) {
                int idx = (i + k < e) ? (i + k) : (e - 1);
                ed[k] = edges[idx];
            }
            float v[8];
            #pragma unroll
            for (int k = 0; k < 8; ++k) v[k] = hin[(ed[k].x << 6) + lane];
            #pragma unroll
            for (int k = 0; k < 8; ++k) {
                float w = (i + k < e) ? __uint_as_float(ed[k].y) : 0.f;
                acc = fmaf(w, v[k], acc);
            }
        }
        tile[m * 68 + lane] = acc;
    }
    __syncthreads();

    // ---- transform phase: A-frags from LDS, bf16 hi/lo split ----
    int mrow = lane & 15, quad = lane >> 4;
    const float* arow = &tile[mrow * 68];
    float4 a0 = *(const float4*)(arow + (quad << 3));
    float4 a1 = *(const float4*)(arow + (quad << 3) + 4);
    float4 a2 = *(const float4*)(arow + 32 + (quad << 3));
    float4 a3 = *(const float4*)(arow + 32 + (quad << 3) + 4);
    float av0[8] = {a0.x, a0.y, a0.z, a0.w, a1.x, a1.y, a1.z, a1.w};
    float av1[8] = {a2.x, a2.y, a2.z, a2.w, a3.x, a3.y, a3.z, a3.w};
    short8 Ah0, Al0, Ah1, Al1;
    #pragma unroll
    for (int j = 0; j < 8; ++j) {
        unsigned short h0 = f2bf(av0[j]);
        Ah0[j] = (short)h0; Al0[j] = (short)f2bf(av0[j] - bf2f(h0));
        unsigned short h1 = f2bf(av1[j]);
        Ah1[j] = (short)h1; Al1[j] = (short)f2bf(av1[j] - bf2f(h1));
    }
    float bias = wf[boff + (wv << 4) + mrow];
    f32x4 c = {bias, bias, bias, bias};
    c = __builtin_amdgcn_mfma_f32_16x16x32_bf16(Ah0, Bh0, c, 0, 0, 0);
    c = __builtin_amdgcn_mfma_f32_16x16x32_bf16(Al0, Bh0, c, 0, 0, 0);
    c = __builtin_amdgcn_mfma_f32_16x16x32_bf16(Ah0, Bl0, c, 0, 0, 0);
    c = __builtin_amdgcn_mfma_f32_16x16x32_bf16(Ah1, Bh1, c, 0, 0, 0);
    c = __builtin_amdgcn_mfma_f32_16x16x32_bf16(Al1, Bh1, c, 0, 0, 0);
    c = __builtin_amdgcn_mfma_f32_16x16x32_bf16(Ah1, Bl1, c, 0, 0, 0);

    // D layout: lane holds D[node m = quad*4+r][feat n = wv*16 + mrow]
    if (!FUSE) {
        #pragma unroll
        for (int r = 0; r < 4; ++r) {
            float o = tanh_fast(c[r]);
            int node = tbase + (quad << 2) + r;
            hout[(node << 6) + (wv << 4) + mrow] = o;
        }
    } else {
        float w4v = wf[W4OFF + (wv << 4) + mrow];
        #pragma unroll
        for (int r = 0; r < 4; ++r) {
            float d = tanh_fast(c[r]) * w4v;
            d += __shfl_xor(d, 1); d += __shfl_xor(d, 2);
            d += __shfl_xor(d, 4); d += __shfl_xor(d, 8);
            if (mrow == 0) pd[wv][(quad << 2) + r] = d;
        }
        __syncthreads();
        if (threadIdx.x < 16)
            s4[tbase + threadIdx.x] = pd[0][threadIdx.x] + pd[1][threadIdx.x]
                                    + pd[2][threadIdx.x] + pd[3][threadIdx.x];
    }
}

// ---- final propagation (1 feat) + RK4 stage combination ----
__global__ __launch_bounds__(256) void k_prop(
        const float* __restrict__ s4, const uint2* __restrict__ edges, const int* __restrict__ rowp,
        const float* __restrict__ wf,
        float* yin, float* yb, float* kA, float* kB, float* kC,
        float c1, float c2, float c3, float c4, int stage,
        const int* __restrict__ modes, void* out, int hidx) {
    int lane = threadIdx.x & 63;
    int n = blockIdx.x * 4 + (threadIdx.x >> 6);
    int s = rowp[n], e = rowp[n + 1];
    float acc = 0.f;
    for (int i = s + lane; i < e; i += 64) {
        uint2 ed = edges[i];
        acc += __uint_as_float(ed.y) * s4[ed.x];
    }
    #pragma unroll
    for (int off = 32; off; off >>= 1) acc += __shfl_xor(acc, off);
    if (lane == 0) {
        float k = acc + wf[B4OFF];
        float ynew = yb[n] + c1 * kA[n] + c2 * kB[n] + c3 * kC[n] + c4 * k;
        if (stage == 0) kA[n] = k;
        else if (stage == 1) kB[n] = k;
        else if (stage == 2) kC[n] = k;
        yin[n] = ynew;
        if (stage == 3) {
            yb[n] = ynew;
            if (modes[0]) ((__hip_bfloat16*)out)[n * HOR + hidx] = __float2bfloat16(ynew);
            else          ((float*)out)[n * HOR + hidx] = ynew;
        }
    }
}

extern "C" void kernel_launch(void* const* d_in, const int* in_sizes, int n_in,
                              void* d_out, int out_size, void* d_ws, size_t ws_size,
                              hipStream_t stream) {
    char* ws = (char*)d_ws;
    uint2* edges = (uint2*)(ws + OFF_EDGES);
    float* hA   = (float*)(ws + OFF_HA);
    float* hB   = (float*)(ws + OFF_HB);
    float* yin  = (float*)(ws + OFF_YIN);
    float* yb   = (float*)(ws + OFF_YB);
    float* kA   = (float*)(ws + OFF_KA);
    float* kB   = (float*)(ws + OFF_KB);
    float* kC   = (float*)(ws + OFF_KC);
    float* s4   = (float*)(ws + OFF_S4);
    int*   deg  = (int*)(ws + OFF_DEG);
    int*   cur  = (int*)(ws + OFF_CUR);
    int*   rowp = (int*)(ws + OFF_ROWP);
    float* dinv = (float*)(ws + OFF_DINV);
    int*   modes= (int*)(ws + OFF_MODES);
    float* wf   = (float*)(ws + OFF_WF);
    short8* wfrag = (short8*)(ws + OFF_WFRAG);

    const void* x    = d_in[0];
    const void* eidx = d_in[1];
    WPtrs wp;
    for (int i = 0; i < 10; ++i) wp.p[i] = d_in[2 + i];

    k_detect  <<<1, 64, 0, stream>>>(x, eidx, modes);
    k_init    <<<(BN + 255) / 256, 256, 0, stream>>>(deg);
    k_count   <<<EB / 256, 256, 0, stream>>>(eidx, modes, deg);
    k_scan    <<<1, 1024, 0, stream>>>(deg, rowp);
    k_finalize<<<(BN + 255) / 256, 256, 0, stream>>>(deg, rowp, cur, dinv, x, modes, yin, yb, d_out);
    k_convert <<<(WFTOT + 255) / 256, 256, 0, stream>>>(wp, wf, modes);
    k_mkfrag  <<<12, 256, 0, stream>>>(wf, wfrag);
    k_scatter <<<(EB + BN + 255) / 256, 256, 0, stream>>>(eidx, modes, dinv, cur, edges);

    const float dt = 10.f / 9.f, dt3 = dt / 3.f;
    const float C[4][4] = {
        {0.f,        0.f,         0.f,         dt3},
        {-dt3,       0.f,         0.f,         dt},
        {dt,         -dt,         0.f,         dt},
        {dt * 0.125f, dt * 0.375f, dt * 0.375f, dt * 0.125f}
    };

    for (int step = 0; step < NSTEP; ++step) {
        for (int st = 0; st < 4; ++st) {
            k_layer0  <<<BN / 4, 256, 0, stream>>>(yin, hA, edges, rowp, wf);
            k_layer<0><<<BN / 16, 256, 0, stream>>>(hA, hB, nullptr, edges, rowp, wf, wfrag, 0, B1OFF);
            k_layer<0><<<BN / 16, 256, 0, stream>>>(hB, hA, nullptr, edges, rowp, wf, wfrag, 1, B2OFF);
            k_layer<1><<<BN / 16, 256, 0, stream>>>(hA, nullptr, s4, edges, rowp, wf, wfrag, 2, B3OFF);
            k_prop    <<<BN / 4, 256, 0, stream>>>(s4, edges, rowp, wf, yin, yb, kA, kB, kC,
                                                   C[st][0], C[st][1], C[st][2], C[st][3], st,
                                                   modes, d_out, step + 1);
        }
    }
}

// Round 4
// 1791.606 us; speedup vs baseline: 3.1113x; 2.0613x over previous
//
#include <hip/hip_runtime.h>
#include <hip/hip_bf16.h>

#define NNODE   2000
#define NG      8
#define EPG     64000
#define TSTEPS  24
#define HOR     10
#define NSTEP   (HOR-1)
#define PITCH   2048          // per-graph node pitch (2000 real + pads; row 2047 is the zero row)
#define ECAP    98304         // padded single-graph CSR capacity (ushorts); sum((deg+15)&~15) <= 96000

// ---- workspace layout (bytes) ----
#define OFF_DESC    0            // ushort * ECAP = 196,608
#define OFF_HA      196608       // bf16 * NG*PITCH*64 = 2,097,152
#define OFF_HB      2293760
#define OFF_YIN     4390912      // float * NG*PITCH = 65,536
#define OFF_YB      4456448
#define OFF_KA      4521984
#define OFF_KB      4587520
#define OFF_KC      4653056
#define OFF_S4      4718592
#define OFF_DEG     4784128      // int * PITCH
#define OFF_CUR     4792320
#define OFF_ROWP    4800512      // int * (PITCH+1) (+pad)
#define OFF_DINV    4808960      // float * PITCH
#define OFF_MODES   4817152      // int[2]
#define OFF_WF      4817408      // fp32 weights, 12673 floats (+pad)
#define OFF_WFRAG   4868352      // bf16 hi/lo MFMA frags: 3 mats * 8192 shorts = 49,152
// total ~4.92 MB

#define W0OFF 0
#define B0OFF 64
#define W1OFF 128
#define B1OFF 4224
#define W2OFF 4288
#define B2OFF 8384
#define W3OFF 8448
#define B3OFF 12544
#define W4OFF 12608
#define B4OFF 12672
#define WFTOT 12673

typedef __attribute__((ext_vector_type(8))) short short8;
typedef __attribute__((ext_vector_type(8))) unsigned short u16x8;
typedef __attribute__((ext_vector_type(4))) float f32x4;

struct WPtrs { const void* p[10]; };

__device__ inline float tanh_fast(float x) {
    float xc = fminf(fmaxf(x, -15.f), 15.f);
    float e  = __expf(2.f * xc);
    return 1.f - 2.f / (e + 1.f);
}
__device__ inline unsigned short f2bf(float f) {
    unsigned u = __float_as_uint(f);
    u += 0x7fff + ((u >> 16) & 1);
    return (unsigned short)(u >> 16);
}
__device__ inline float bf2f(unsigned short h) {
    return __uint_as_float(((unsigned)h) << 16);
}
__device__ inline int ld_idx(const void* p, long i, int imode) {
    return imode ? (int)((const long long*)p)[i] : ((const int*)p)[i];
}

// ---- dtype detection ----
__global__ void k_detect(const void* x, const void* eidx, int* modes) {
    int lane = threadIdx.x;
    const unsigned* xw = (const unsigned*)x;
    unsigned w = xw[lane];
    int ex = (w >> 7) & 0xFF;
    unsigned long long m = __ballot(ex >= 100 && ex <= 145);
    const unsigned* ew = (const unsigned*)eidx;
    unsigned long long m2 = __ballot(ew[2*lane + 1] != 0);
    if (lane == 0) {
        modes[0] = (__popcll(m) >= 48) ? 1 : 0;
        modes[1] = (__popcll(m2) == 0) ? 1 : 0;
    }
}

__global__ void k_init(int* deg) {
    int n = blockIdx.x * 256 + threadIdx.x;
    if (n < PITCH) deg[n] = (n < NNODE) ? 1 : 0;   // self-loop for real nodes
}

__global__ void k_count(const void* eidx, const int* __restrict__ modes, int* deg) {
    int e = blockIdx.x * 256 + threadIdx.x;        // EPG threads, single graph
    int imode = modes[1];
    int dst = ld_idx(eidx, (long)EPG + e, imode);
    atomicAdd(&deg[dst], 1);
}

// single-graph scan over PITCH entries; also cursor + dinv
__global__ __launch_bounds__(256) void k_scan(const int* __restrict__ deg, int* rowp,
                                              int* cursor, float* dinv) {
    __shared__ int part[256];
    int t = threadIdx.x, base = t * 8;
    int loc[8]; int s = 0;
    #pragma unroll
    for (int k = 0; k < 8; ++k) {
        int d = deg[base + k];
        int p = (d + 15) & ~15;        // pad rows to x16 edges (16B-aligned desc)
        loc[k] = p; s += p;
    }
    part[t] = s; __syncthreads();
    for (int off = 1; off < 256; off <<= 1) {
        int v = (t >= off) ? part[t - off] : 0;
        __syncthreads();
        part[t] += v;
        __syncthreads();
    }
    int run = part[t] - s;
    #pragma unroll
    for (int k = 0; k < 8; ++k) {
        rowp[base + k] = run; cursor[base + k] = run;
        int d = deg[base + k];
        dinv[base + k] = (d > 0) ? rsqrtf((float)d) : 0.f;
        run += loc[k];
    }
    if (t == 255) rowp[PITCH] = part[255];
}

// fill desc with sentinel 2047 (zero row) so pad slots contribute 0 with no masking
__global__ void k_edgefill(unsigned* desc32) {
    int i = blockIdx.x * 256 + threadIdx.x;
    if (i < ECAP / 2) desc32[i] = 0x07FF07FFu;
}

__global__ void k_scatter(const void* eidx, const int* __restrict__ modes,
                          int* cursor, unsigned short* desc) {
    int idx = blockIdx.x * 256 + threadIdx.x;
    if (idx >= EPG + NNODE) return;
    int imode = modes[1];
    int s, d;
    if (idx < EPG) { s = ld_idx(eidx, idx, imode); d = ld_idx(eidx, (long)EPG + idx, imode); }
    else           { s = idx - EPG; d = s; }
    int pos = atomicAdd(&cursor[d], 1);
    desc[pos] = (unsigned short)s;
}

__global__ void k_convert(WPtrs wp, float* wf, const int* __restrict__ modes) {
    int idx = blockIdx.x * 256 + threadIdx.x;
    if (idx >= WFTOT) return;
    int fmode = modes[0];
    const int offs[10]  = {W0OFF,B0OFF,W1OFF,B1OFF,W2OFF,B2OFF,W3OFF,B3OFF,W4OFF,B4OFF};
    const int sizes[10] = {64,64,4096,64,4096,64,4096,64,64,1};
    #pragma unroll
    for (int s = 0; s < 10; ++s) {
        if (idx >= offs[s] && idx < offs[s] + sizes[s]) {
            int j = idx - offs[s];
            wf[idx] = fmode ? __bfloat162float(((const __hip_bfloat16*)wp.p[s])[j])
                            : ((const float*)wp.p[s])[j];
        }
    }
}

// B-fragments for W1,W2,W3 (bf16 hi/lo, MFMA order) — unchanged from R3
__global__ void k_mkfrag(const float* __restrict__ wf, short8* frag) {
    int t = blockIdx.x * 256 + threadIdx.x;
    if (t >= 3072) return;
    int lane = t & 63, half = (t >> 6) & 1, kh = (t >> 7) & 1, nb = (t >> 8) & 3, mat = t >> 10;
    const int woffs[3] = {W1OFF, W2OFF, W3OFF};
    const float* W = wf + woffs[mat];
    int n  = nb * 16 + (lane & 15);
    int k0 = kh * 32 + (lane >> 4) * 8;
    short8 v;
    #pragma unroll
    for (int j = 0; j < 8; ++j) {
        float w = W[(k0 + j) * 64 + n];
        unsigned short h = f2bf(w);
        v[j] = half ? (short)f2bf(w - bf2f(h)) : (short)h;
    }
    frag[t] = v;
}

// zero the pad rows (2000..2047) of both h buffers (re-poisoned each launch)
__global__ void k_hpad(unsigned* hA32, unsigned* hB32) {
    int idx = blockIdx.x * 256 + threadIdx.x;     // 2 * 8 * 48 * 32 = 24576
    if (idx >= 2 * NG * 48 * 32) return;
    int b = idx / (NG * 48 * 32), r = idx % (NG * 48 * 32);
    int g = r / (48 * 32), rr = r % (48 * 32);
    int row = NNODE + rr / 32, fp = rr % 32;
    unsigned* p = b ? hB32 : hA32;
    p[(g * PITCH + row) * 32 + fp] = 0;
}

// per-node init: yin' = dinv*y0, yb = y0, out[:,0] = y0; pads -> zeros (incl s4)
__global__ void k_finalize(const float* __restrict__ dinv, const void* x,
                           const int* __restrict__ modes,
                           float* yin, float* yb, float* s4, void* out) {
    int idx = blockIdx.x * 256 + threadIdx.x;     // NG*PITCH
    if (idx >= NG * PITCH) return;
    int g = idx >> 11, local = idx & (PITCH - 1);
    if (local >= NNODE) { yin[idx] = 0.f; yb[idx] = 0.f; s4[idx] = 0.f; return; }
    int cn = g * NNODE + local;
    float y0 = modes[0] ? __bfloat162float(((const __hip_bfloat16*)x)[cn * TSTEPS + (TSTEPS - 1)])
                        : ((const float*)x)[cn * TSTEPS + (TSTEPS - 1)];
    yin[idx] = dinv[local] * y0;
    yb[idx]  = y0;
    if (modes[0]) ((__hip_bfloat16*)out)[cn * HOR] = __float2bfloat16(y0);
    else          ((float*)out)[cn * HOR] = y0;
}

// ---- layer 0: scalar gather of yin' -> h0' (bf16). block b -> graph b&7 (XCD locality) ----
__global__ __launch_bounds__(256) void k_layer0(
        const float* __restrict__ yin, unsigned short* __restrict__ hout,
        const unsigned short* __restrict__ desc, const int* __restrict__ rowp,
        const float* __restrict__ dinv, const float* __restrict__ wf) {
    int lane = threadIdx.x & 63, wv = threadIdx.x >> 6;
    int b = blockIdx.x;
    int g = b & 7, local = (b >> 3) * 4 + wv;     // 4000 blocks -> 8 graphs x 2000 nodes
    const float* yg = yin + g * PITCH;
    int s = rowp[local], e = rowp[local + 1];
    float acc = 0.f;
    for (int i = s + lane; i < e; i += 64) acc += yg[desc[i]];   // pads hit zero row
    #pragma unroll
    for (int off = 32; off; off >>= 1) acc += __shfl_xor(acc, off);
    float dv = dinv[local];
    float o = dv * tanh_fast(dv * acc * wf[W0OFF + lane] + wf[B0OFF + lane]);
    hout[((g * PITCH + local) << 6) + lane] = f2bf(o);
}

// ---- middle layers: 16-node tile; bf16 gather (no predication) -> LDS -> MFMA ----
template<int FUSE>
__global__ __launch_bounds__(256, 4) void k_layer(
        const unsigned short* __restrict__ hin, unsigned short* __restrict__ hout,
        float* __restrict__ s4,
        const unsigned short* __restrict__ desc, const int* __restrict__ rowp,
        const float* __restrict__ dinv, const float* __restrict__ wf,
        const short8* __restrict__ frag, int mat, int boff) {
    __shared__ float tile[16 * 68];
    __shared__ float dinvt[16];
    __shared__ float pd[4][16];
    int lane = threadIdx.x & 63, wv = threadIdx.x >> 6;
    int b = blockIdx.x;
    int g = b & 7, tb = (b >> 3) << 4;            // 1000 blocks = 8 graphs x 125 tiles
    const unsigned short* hg = hin + ((size_t)g * PITCH << 6);

    const short8* fb = frag + (mat << 10);
    short8 Bh0 = fb[(wv << 8) + 0 * 128 + 0 * 64 + lane];
    short8 Bl0 = fb[(wv << 8) + 0 * 128 + 1 * 64 + lane];
    short8 Bh1 = fb[(wv << 8) + 1 * 128 + 0 * 64 + lane];
    short8 Bl1 = fb[(wv << 8) + 1 * 128 + 1 * 64 + lane];

    // gather: 4 rows per wave, 16 bf16 row-loads in flight, zero predication
    #pragma unroll
    for (int r = 0; r < 4; ++r) {
        int m = (wv << 2) + r;
        int local = tb + m;
        int s = rowp[local], e = rowp[local + 1];   // both multiples of 16
        float acc = 0.f;
        for (int i = s; i < e; i += 16) {
            u16x8 d0 = *(const u16x8*)(desc + i);
            u16x8 d1 = *(const u16x8*)(desc + i + 8);
            unsigned short v[16];
            #pragma unroll
            for (int k = 0; k < 8; ++k) v[k]     = hg[(((unsigned)d0[k]) << 6) + lane];
            #pragma unroll
            for (int k = 0; k < 8; ++k) v[8 + k] = hg[(((unsigned)d1[k]) << 6) + lane];
            #pragma unroll
            for (int k = 0; k < 16; ++k) acc += bf2f(v[k]);
        }
        float dv = dinv[local];
        tile[m * 68 + lane] = acc * dv;             // dst-side normalization
        if (lane == 0) dinvt[m] = dv;
    }
    __syncthreads();

    // transform: A from LDS (bf16 hi/lo split), W frags preloaded
    int mrow = lane & 15, quad = lane >> 4;
    const float* arow = &tile[mrow * 68];
    float4 a0 = *(const float4*)(arow + (quad << 3));
    float4 a1 = *(const float4*)(arow + (quad << 3) + 4);
    float4 a2 = *(const float4*)(arow + 32 + (quad << 3));
    float4 a3 = *(const float4*)(arow + 32 + (quad << 3) + 4);
    float av0[8] = {a0.x, a0.y, a0.z, a0.w, a1.x, a1.y, a1.z, a1.w};
    float av1[8] = {a2.x, a2.y, a2.z, a2.w, a3.x, a3.y, a3.z, a3.w};
    short8 Ah0, Al0, Ah1, Al1;
    #pragma unroll
    for (int j = 0; j < 8; ++j) {
        unsigned short h0 = f2bf(av0[j]);
        Ah0[j] = (short)h0; Al0[j] = (short)f2bf(av0[j] - bf2f(h0));
        unsigned short h1 = f2bf(av1[j]);
        Ah1[j] = (short)h1; Al1[j] = (short)f2bf(av1[j] - bf2f(h1));
    }
    float bias = wf[boff + (wv << 4) + mrow];
    f32x4 c = {bias, bias, bias, bias};
    c = __builtin_amdgcn_mfma_f32_16x16x32_bf16(Ah0, Bh0, c, 0, 0, 0);
    c = __builtin_amdgcn_mfma_f32_16x16x32_bf16(Al0, Bh0, c, 0, 0, 0);
    c = __builtin_amdgcn_mfma_f32_16x16x32_bf16(Ah0, Bl0, c, 0, 0, 0);
    c = __builtin_amdgcn_mfma_f32_16x16x32_bf16(Ah1, Bh1, c, 0, 0, 0);
    c = __builtin_amdgcn_mfma_f32_16x16x32_bf16(Al1, Bh1, c, 0, 0, 0);
    c = __builtin_amdgcn_mfma_f32_16x16x32_bf16(Ah1, Bl1, c, 0, 0, 0);

    if (!FUSE) {
        #pragma unroll
        for (int r = 0; r < 4; ++r) {
            int m = (quad << 2) + r;
            float o = dinvt[m] * tanh_fast(c[r]);   // src-side pre-scale for next layer
            hout[(((size_t)g * PITCH + tb + m) << 6) + (wv << 4) + mrow] = f2bf(o);
        }
    } else {
        float w4v = wf[W4OFF + (wv << 4) + mrow];
        #pragma unroll
        for (int r = 0; r < 4; ++r) {
            float d = tanh_fast(c[r]) * w4v;
            d += __shfl_xor(d, 1); d += __shfl_xor(d, 2);
            d += __shfl_xor(d, 4); d += __shfl_xor(d, 8);
            if (mrow == 0) pd[wv][(quad << 2) + r] = d;
        }
        __syncthreads();
        if (threadIdx.x < 16)
            s4[g * PITCH + tb + threadIdx.x] = dinvt[threadIdx.x] *
                (pd[0][threadIdx.x] + pd[1][threadIdx.x] + pd[2][threadIdx.x] + pd[3][threadIdx.x]);
    }
}

// ---- final propagation + RK4 stage combine ----
__global__ __launch_bounds__(256) void k_prop(
        const float* __restrict__ s4, const unsigned short* __restrict__ desc,
        const int* __restrict__ rowp, const float* __restrict__ dinv,
        const float* __restrict__ wf,
        float* yin, float* yb, float* kA, float* kB, float* kC,
        float c1, float c2, float c3, float c4, int stage,
        const int* __restrict__ modes, void* out, int hidx) {
    int lane = threadIdx.x & 63, wv = threadIdx.x >> 6;
    int b = blockIdx.x;
    int g = b & 7, local = (b >> 3) * 4 + wv;
    const float* sg = s4 + g * PITCH;
    int s = rowp[local], e = rowp[local + 1];
    float acc = 0.f;
    for (int i = s + lane; i < e; i += 64) acc += sg[desc[i]];
    #pragma unroll
    for (int off = 32; off; off >>= 1) acc += __shfl_xor(acc, off);
    if (lane == 0) {
        int idx = g * PITCH + local;
        float dv = dinv[local];
        float k = dv * acc + wf[B4OFF];
        float ynew = yb[idx] + c1 * kA[idx] + c2 * kB[idx] + c3 * kC[idx] + c4 * k;
        if (stage == 0) kA[idx] = k;
        else if (stage == 1) kB[idx] = k;
        else if (stage == 2) kC[idx] = k;
        yin[idx] = dv * ynew;                      // pre-scaled for next layer0 gather
        if (stage == 3) {
            yb[idx] = ynew;
            int cn = g * NNODE + local;
            if (modes[0]) ((__hip_bfloat16*)out)[cn * HOR + hidx] = __float2bfloat16(ynew);
            else          ((float*)out)[cn * HOR + hidx] = ynew;
        }
    }
}

extern "C" void kernel_launch(void* const* d_in, const int* in_sizes, int n_in,
                              void* d_out, int out_size, void* d_ws, size_t ws_size,
                              hipStream_t stream) {
    char* ws = (char*)d_ws;
    unsigned short* desc = (unsigned short*)(ws + OFF_DESC);
    unsigned short* hA   = (unsigned short*)(ws + OFF_HA);
    unsigned short* hB   = (unsigned short*)(ws + OFF_HB);
    float* yin  = (float*)(ws + OFF_YIN);
    float* yb   = (float*)(ws + OFF_YB);
    float* kA   = (float*)(ws + OFF_KA);
    float* kB   = (float*)(ws + OFF_KB);
    float* kC   = (float*)(ws + OFF_KC);
    float* s4   = (float*)(ws + OFF_S4);
    int*   deg  = (int*)(ws + OFF_DEG);
    int*   cur  = (int*)(ws + OFF_CUR);
    int*   rowp = (int*)(ws + OFF_ROWP);
    float* dinv = (float*)(ws + OFF_DINV);
    int*   modes= (int*)(ws + OFF_MODES);
    float* wf   = (float*)(ws + OFF_WF);
    short8* wfrag = (short8*)(ws + OFF_WFRAG);

    const void* x    = d_in[0];
    const void* eidx = d_in[1];
    WPtrs wp;
    for (int i = 0; i < 10; ++i) wp.p[i] = d_in[2 + i];

    k_detect  <<<1, 64, 0, stream>>>(x, eidx, modes);
    k_init    <<<PITCH / 256, 256, 0, stream>>>(deg);
    k_count   <<<EPG / 256, 256, 0, stream>>>(eidx, modes, deg);
    k_scan    <<<1, 256, 0, stream>>>(deg, rowp, cur, dinv);
    k_edgefill<<<(ECAP / 2 + 255) / 256, 256, 0, stream>>>((unsigned*)desc);
    k_scatter <<<(EPG + NNODE + 255) / 256, 256, 0, stream>>>(eidx, modes, cur, desc);
    k_convert <<<(WFTOT + 255) / 256, 256, 0, stream>>>(wp, wf, modes);
    k_mkfrag  <<<12, 256, 0, stream>>>(wf, wfrag);
    k_hpad    <<<96, 256, 0, stream>>>((unsigned*)hA, (unsigned*)hB);
    k_finalize<<<NG * PITCH / 256, 256, 0, stream>>>(dinv, x, modes, yin, yb, s4, d_out);

    const float dt = 10.f / 9.f, dt3 = dt / 3.f;
    const float C[4][4] = {
        {0.f,        0.f,         0.f,         dt3},
        {-dt3,       0.f,         0.f,         dt},
        {dt,         -dt,         0.f,         dt},
        {dt * 0.125f, dt * 0.375f, dt * 0.375f, dt * 0.125f}
    };

    for (int step = 0; step < NSTEP; ++step) {
        for (int st = 0; st < 4; ++st) {
            k_layer0  <<<4000, 256, 0, stream>>>(yin, hA, desc, rowp, dinv, wf);
            k_layer<0><<<1000, 256, 0, stream>>>(hA, hB, nullptr, desc, rowp, dinv, wf, wfrag, 0, B1OFF);
            k_layer<0><<<1000, 256, 0, stream>>>(hB, hA, nullptr, desc, rowp, dinv, wf, wfrag, 1, B2OFF);
            k_layer<1><<<1000, 256, 0, stream>>>(hA, nullptr, s4, desc, rowp, dinv, wf, wfrag, 2, B3OFF);
            k_prop    <<<4000, 256, 0, stream>>>(s4, desc, rowp, dinv, wf, yin, yb, kA, kB, kC,
                                                 C[st][0], C[st][1], C[st][2], C[st][3], st,
                                                 modes, d_out, step + 1);
        }
    }
}